// Round 1
// baseline (137.989 us; speedup 1.0000x reference)
//
#include <hip/hip_runtime.h>
#include <math.h>

namespace {
constexpr int kB = 16;
constexpr int kL = 240000;
constexpr int kD = 9;
constexpr float kSamp = 24000.0f;
constexpr int kChunk = 2048;
constexpr int kT = 8;              // samples per thread
constexpr int kThreads = 256;      // kChunk / kT
constexpr int kNChunks = (kL + kChunk - 1) / kChunk;  // 118
constexpr float kTwoPi = 6.28318530717958647692f;
constexpr float kSineAmp = 0.1f;
constexpr float kNoiseStd = 0.003f;
constexpr float kNoiseUnv = (float)(0.1 / 3.0);
}  // namespace

// Pass A: per-chunk partial sums of rad values (double), per (b, chunk, d).
__global__ __launch_bounds__(kThreads) void sine_pass_a(
    const float* __restrict__ f0, const float* __restrict__ rand_ini,
    double* __restrict__ part) {
  const int c = blockIdx.x, b = blockIdx.y, tid = threadIdx.x;
  const int l0 = c * kChunk + tid * kT;
  double acc[kD];
#pragma unroll
  for (int d = 0; d < kD; ++d) acc[d] = 0.0;
  if (l0 < kL) {  // full 8-groups only (384-sample tail chunk is 48 full groups)
    const float4* f4 =
        reinterpret_cast<const float4*>(f0 + (size_t)b * kL + l0);
    const float4 a = f4[0], bb = f4[1];
    const float fv[kT] = {a.x, a.y, a.z, a.w, bb.x, bb.y, bb.z, bb.w};
#pragma unroll
    for (int j = 0; j < kT; ++j) {
      const float rq = fv[j] / kSamp;
#pragma unroll
      for (int d = 0; d < kD; ++d) acc[d] += (double)(rq * (float)(d + 1));
    }
    if (l0 == 0) {
#pragma unroll
      for (int d = 0; d < kD; ++d) acc[d] += (double)rand_ini[b * kD + d];
    }
  }
  __shared__ double red[kThreads * kD];
#pragma unroll
  for (int d = 0; d < kD; ++d) red[tid * kD + d] = acc[d];
  __syncthreads();
  for (int ofs = kThreads / 2; ofs > 0; ofs >>= 1) {
    if (tid < ofs) {
#pragma unroll
      for (int d = 0; d < kD; ++d)
        red[tid * kD + d] += red[(tid + ofs) * kD + d];
    }
    __syncthreads();
  }
  if (tid < kD) part[((size_t)b * kNChunks + c) * kD + tid] = red[tid];
}

// Pass B: exclusive scan of the chunk partials along chunks, per (b, d) chain.
__global__ __launch_bounds__(128) void sine_pass_b(double* __restrict__ part) {
  const int chain = blockIdx.x;  // 0 .. kB*kD-1
  const int b = chain / kD, d = chain % kD;
  const int tid = threadIdx.x;
  __shared__ double s[128];
  double v = 0.0;
  if (tid < kNChunks) v = part[((size_t)b * kNChunks + tid) * kD + d];
  s[tid] = v;
  __syncthreads();
#pragma unroll
  for (int ofs = 1; ofs < 128; ofs <<= 1) {
    const double t = (tid >= ofs) ? s[tid - ofs] : 0.0;
    __syncthreads();
    s[tid] += t;
    __syncthreads();
  }
  if (tid < kNChunks)
    part[((size_t)b * kNChunks + tid) * kD + d] = s[tid] - v;  // exclusive
}

// Pass C: recompute local sums, LDS scan for per-thread bases, then emit
// sin/noise/merge/tanh output.
__global__ __launch_bounds__(kThreads) void sine_pass_c(
    const float* __restrict__ f0, const float* __restrict__ rand_ini,
    const float* __restrict__ noise, const float* __restrict__ w,
    const double* __restrict__ part, float* __restrict__ out) {
  const int c = blockIdx.x, b = blockIdx.y, tid = threadIdx.x;
  const int l0 = c * kChunk + tid * kT;
  const bool active = l0 < kL;
  float fv[kT];
  double acc[kD];
#pragma unroll
  for (int d = 0; d < kD; ++d) acc[d] = 0.0;
  if (active) {
    const float4* f4 =
        reinterpret_cast<const float4*>(f0 + (size_t)b * kL + l0);
    const float4 a = f4[0], bb = f4[1];
    fv[0] = a.x; fv[1] = a.y; fv[2] = a.z; fv[3] = a.w;
    fv[4] = bb.x; fv[5] = bb.y; fv[6] = bb.z; fv[7] = bb.w;
#pragma unroll
    for (int j = 0; j < kT; ++j) {
      const float rq = fv[j] / kSamp;
#pragma unroll
      for (int d = 0; d < kD; ++d) acc[d] += (double)(rq * (float)(d + 1));
    }
    if (l0 == 0) {
#pragma unroll
      for (int d = 0; d < kD; ++d) acc[d] += (double)rand_ini[b * kD + d];
    }
  } else {
#pragma unroll
    for (int j = 0; j < kT; ++j) fv[j] = 0.0f;
  }

  __shared__ double sc[kThreads * kD];
#pragma unroll
  for (int d = 0; d < kD; ++d) sc[tid * kD + d] = acc[d];
  __syncthreads();
  for (int ofs = 1; ofs < kThreads; ofs <<= 1) {
    double t[kD];
#pragma unroll
    for (int d = 0; d < kD; ++d)
      t[d] = (tid >= ofs) ? sc[(tid - ofs) * kD + d] : 0.0;
    __syncthreads();
#pragma unroll
    for (int d = 0; d < kD; ++d) sc[tid * kD + d] += t[d];
    __syncthreads();
  }

  if (!active) return;

  double run[kD];
#pragma unroll
  for (int d = 0; d < kD; ++d) {
    // exclusive thread prefix = inclusive - own; plus exclusive chunk base
    run[d] = part[((size_t)b * kNChunks + c) * kD + d] + sc[tid * kD + d] -
             acc[d];
  }

  float wv[kD];
#pragma unroll
  for (int d = 0; d < kD; ++d) wv[d] = w[d];

  float ob[kT];
#pragma unroll
  for (int j = 0; j < kT; ++j) {
    const int l = l0 + j;
    const float f = fv[j];
    const float rq = f / kSamp;
    const float uvf = (f > 0.0f) ? 1.0f : 0.0f;
    const float namp = (f > 0.0f) ? kNoiseStd : kNoiseUnv;
    const size_t nbase = ((size_t)b * kL + l) * kD;
    float dot = 0.0f;
#pragma unroll
    for (int d = 0; d < kD; ++d) {
      double radd = (double)(rq * (float)(d + 1));
      if (l == 0) radd += (double)rand_ini[b * kD + d];
      run[d] += radd;
      const double ph = run[d];
      const float pf = (float)(ph - floor(ph));
      float sv = sinf(pf * kTwoPi) * kSineAmp;
      const float nz = noise[nbase + d];
      sv = sv * uvf + namp * nz;
      dot += sv * wv[d];
    }
    ob[j] = tanhf(dot);
  }

  float4* o4 = reinterpret_cast<float4*>(out + (size_t)b * kL + l0);
  o4[0] = make_float4(ob[0], ob[1], ob[2], ob[3]);
  o4[1] = make_float4(ob[4], ob[5], ob[6], ob[7]);
}

extern "C" void kernel_launch(void* const* d_in, const int* in_sizes, int n_in,
                              void* d_out, int out_size, void* d_ws,
                              size_t ws_size, hipStream_t stream) {
  const float* f0 = (const float*)d_in[0];
  const float* rand_ini = (const float*)d_in[1];
  const float* noise = (const float*)d_in[2];
  const float* w = (const float*)d_in[3];
  float* out = (float*)d_out;
  double* part = (double*)d_ws;  // kB * kNChunks * kD doubles = 135936 B

  const dim3 grid(kNChunks, kB), block(kThreads);
  sine_pass_a<<<grid, block, 0, stream>>>(f0, rand_ini, part);
  sine_pass_b<<<dim3(kB * kD), dim3(128), 0, stream>>>(part);
  sine_pass_c<<<grid, block, 0, stream>>>(f0, rand_ini, noise, w, part, out);
}

// Round 2
// 37.455 us; speedup vs baseline: 3.6841x; 3.6841x over previous
//
#include <hip/hip_runtime.h>
#include <math.h>

namespace {
constexpr int kB = 16;
constexpr int kL = 240000;
constexpr int kD = 9;
constexpr float kInvSamp = 1.0f / 24000.0f;
constexpr int kChunk = 2048;
constexpr int kT = 8;              // samples per thread
constexpr int kThreads = 256;      // kChunk / kT
constexpr int kNChunks = (kL + kChunk - 1) / kChunk;  // 118 (last chunk: 384)
constexpr float kSineAmp = 0.1f;
constexpr float kNoiseStd = 0.003f;
constexpr float kNoiseUnv = (float)(0.1 / 3.0);
}  // namespace

// ---------------- Pass A: per-chunk sum of rq = f0/SR (one double per chunk)
__global__ __launch_bounds__(kThreads) void sine_pass_a(
    const float* __restrict__ f0, double* __restrict__ part) {
  const int c = blockIdx.x, b = blockIdx.y, tid = threadIdx.x;
  const int l0 = c * kChunk + tid * kT;
  float s = 0.0f;
  if (l0 < kL) {
    const float4* f4 = reinterpret_cast<const float4*>(f0 + (size_t)b * kL + l0);
    const float4 a = f4[0], bb = f4[1];
    s = ((a.x + a.y) + (a.z + a.w)) + ((bb.x + bb.y) + (bb.z + bb.w));
  }
  __shared__ double red[kThreads];
  red[tid] = (double)s * (double)kInvSamp;
  __syncthreads();
  for (int ofs = kThreads / 2; ofs > 0; ofs >>= 1) {
    if (tid < ofs) red[tid] += red[tid + ofs];
    __syncthreads();
  }
  if (tid == 0) part[(size_t)b * kNChunks + c] = red[0];
}

// ---------------- Pass B: exclusive scan over chunks, one chain per batch
__global__ __launch_bounds__(128) void sine_pass_b(double* __restrict__ part) {
  const int b = blockIdx.x, tid = threadIdx.x;
  __shared__ double s[128];
  double v = 0.0;
  if (tid < kNChunks) v = part[(size_t)b * kNChunks + tid];
  s[tid] = v;
  __syncthreads();
#pragma unroll
  for (int ofs = 1; ofs < 128; ofs <<= 1) {
    const double t = (tid >= ofs) ? s[tid - ofs] : 0.0;
    __syncthreads();
    s[tid] += t;
    __syncthreads();
  }
  if (tid < kNChunks) part[(size_t)b * kNChunks + tid] = s[tid] - v;  // excl
}

// ---------------- Pass C: scan-within-chunk + emit
__global__ __launch_bounds__(kThreads) void sine_pass_c(
    const float* __restrict__ f0, const float* __restrict__ rand_ini,
    const float* __restrict__ noise, const float* __restrict__ w,
    const double* __restrict__ part, float* __restrict__ out) {
  const int c = blockIdx.x, b = blockIdx.y, tid = threadIdx.x;
  const int l0 = c * kChunk + tid * kT;
  const bool active = l0 < kL;

  // f0 -> rq (float), thread-local prefix pieces
  float rq[kT];
  float tsum = 0.0f;
  if (active) {
    const float4* f4 = reinterpret_cast<const float4*>(f0 + (size_t)b * kL + l0);
    const float4 a = f4[0], bb = f4[1];
    rq[0] = a.x * kInvSamp; rq[1] = a.y * kInvSamp;
    rq[2] = a.z * kInvSamp; rq[3] = a.w * kInvSamp;
    rq[4] = bb.x * kInvSamp; rq[5] = bb.y * kInvSamp;
    rq[6] = bb.z * kInvSamp; rq[7] = bb.w * kInvSamp;
#pragma unroll
    for (int j = 0; j < kT; ++j) tsum += rq[j];
  } else {
#pragma unroll
    for (int j = 0; j < kT; ++j) rq[j] = 0.0f;
  }

  // hoist all noise loads: 18 x float4 = 72 floats, contiguous, 16B-aligned
  float nz[kT * kD];
  if (active) {
    const float4* n4 =
        reinterpret_cast<const float4*>(noise + ((size_t)b * kL + l0) * kD);
#pragma unroll
    for (int i = 0; i < 18; ++i) {
      const float4 v = n4[i];
      nz[4 * i + 0] = v.x; nz[4 * i + 1] = v.y;
      nz[4 * i + 2] = v.z; nz[4 * i + 3] = v.w;
    }
  }

  // block-wide inclusive scan of per-thread sums (single double chain)
  __shared__ double sc[kThreads];
  sc[tid] = (double)tsum;
  __syncthreads();
  for (int ofs = 1; ofs < kThreads; ofs <<= 1) {
    const double t = (tid >= ofs) ? sc[tid - ofs] : 0.0;
    __syncthreads();
    sc[tid] += t;
    __syncthreads();
  }

  if (!active) return;

  // exclusive base for this thread's first sample
  const double cbase = part[(size_t)b * kNChunks + c] + sc[tid] - (double)tsum;

  // per-harmonic fractional phase base (double mul+frac once, then float)
  float basef[kD], wv[kD];
#pragma unroll
  for (int d = 0; d < kD; ++d) {
    const double ph = (double)(d + 1) * cbase + (double)rand_ini[b * kD + d];
    basef[d] = (float)(ph - floor(ph));
    wv[d] = w[d];
  }

  float ob[kT];
  float pref = 0.0f;
#pragma unroll
  for (int j = 0; j < kT; ++j) {
    pref += rq[j];  // inclusive local prefix in cycles (<= ~1.2)
    const float f = rq[j];  // rq > 0 iff f0 > 0
    const float au = (f > 0.0f) ? kSineAmp : 0.0f;
    const float namp = (f > 0.0f) ? kNoiseStd : kNoiseUnv;
    float dots = 0.0f, dotn = 0.0f;
#pragma unroll
    for (int d = 0; d < kD; ++d) {
      const float pf = __builtin_amdgcn_fractf(basef[d] + (float)(d + 1) * pref);
      const float sv = __builtin_amdgcn_sinf(pf);  // sin(2*pi*pf)
      dots = fmaf(wv[d], sv, dots);
      dotn = fmaf(wv[d], nz[j * kD + d], dotn);
    }
    const float x = au * dots + namp * dotn;
    const float e = __expf(2.0f * x);
    ob[j] = 1.0f - 2.0f * __builtin_amdgcn_rcpf(e + 1.0f);  // tanh(x)
  }

  float4* o4 = reinterpret_cast<float4*>(out + (size_t)b * kL + l0);
  o4[0] = make_float4(ob[0], ob[1], ob[2], ob[3]);
  o4[1] = make_float4(ob[4], ob[5], ob[6], ob[7]);
}

extern "C" void kernel_launch(void* const* d_in, const int* in_sizes, int n_in,
                              void* d_out, int out_size, void* d_ws,
                              size_t ws_size, hipStream_t stream) {
  const float* f0 = (const float*)d_in[0];
  const float* rand_ini = (const float*)d_in[1];
  const float* noise = (const float*)d_in[2];
  const float* w = (const float*)d_in[3];
  float* out = (float*)d_out;
  double* part = (double*)d_ws;  // kB * kNChunks doubles = 15104 B

  const dim3 grid(kNChunks, kB), block(kThreads);
  sine_pass_a<<<grid, block, 0, stream>>>(f0, part);
  sine_pass_b<<<dim3(kB), dim3(128), 0, stream>>>(part);
  sine_pass_c<<<grid, block, 0, stream>>>(f0, rand_ini, noise, w, part, out);
}